// Round 8
// baseline (820.620 us; speedup 1.0000x reference)
//
#include <hip/hip_runtime.h>

// RGCN R19: sort ELIMINATED — scatter-accumulate replaces sort-then-gather.
// R18 postmortem: fixing sortb's WRITE (37->29MB) was neutral (54.0us): the
// cost is the 8-phase barrier-serialized sort pipeline at 52KB LDS / low
// occupancy, not any single phase. R19: counting sort, stage32, scan, rowseg
// all deleted. sortb = hist + L1 directly from regs via LDS f32 atomics into
// per-dst accumulators (stride 7, gcd(7,32)=1); hist persisted (9MB) for
// l3's mean. l2/l3 become bucket-blocks: linear uint4 region read (L3-hot,
// read 3x, written once), per-record gather + 3/6 LDS f32 atomics (strides
// 5/7), 128-dst finalize. Cost accepted: w4[rel] random again (~5us).

#define NREL   90
#define BSH    7
#define BNODES 128       // nodes per bucket
#define NBINS  1024      // gcount table size
#define NB2    784       // scan bins (49 lanes x 16); buckets <= 782
#define GCH    8704      // edges per chunk = 512*17
#define KPT    17        // edges per thread in group_k
#define SPK    11056     // s_pack slots >= 8704 + 782*3 = 11050 hard max
#define CAPB   10496     // per-bucket region capacity; fill mean 9300 + 12s
#define NV4    6         // ceil(CAPB/4/512) uint4 loads per thread
#define HWORDS (BNODES * NREL / 4)   // 2880 u8-packed hist words
#define SENT   0xFFFFFFFFu

__device__ __forceinline__ float frelu(float v) { return v > 0.0f ? v : 0.0f; }

// ---------- K1: fused pad-x + single-read grouping, padded reservation ----------
// record = src | rel<<17 | dstLocal<<24 ; sentinel unreachable (rel <= 89).
__launch_bounds__(512)
__global__ void group_k(const float* __restrict__ x, float4* __restrict__ x4,
                        int N, int gNp,
                        const int* __restrict__ src, const int* __restrict__ dst,
                        const int* __restrict__ et, int* __restrict__ gcount,
                        unsigned* __restrict__ regions, int E) {
    int tid = threadIdx.x;
    if (blockIdx.x < gNp) {           // pad role
        int i = blockIdx.x * 512 + tid;
        if (i < N) x4[i] = make_float4(x[3 * i], x[3 * i + 1], x[3 * i + 2], 0.0f);
        return;
    }
    __shared__ int s_cur[NB2];        // 4-aligned starts -> place cursor
    __shared__ int s_pend[NB2];       // hist, then padded end (next start)
    __shared__ int s_off[NB2];        // reserved_base - start (multiple of 4)
    __shared__ unsigned s_pack[SPK];  // 44224 B -> total 53632 B (3 blk/CU)
    int chunk = blockIdx.x - gNp;
    int e0 = chunk * GCH;
    int cnt = min(GCH, E - e0);
    for (int i = tid; i < NB2; i += 512) s_pend[i] = 0;
    __syncthreads();
    // single global read: pack records into VGPRs, hist from regs
    unsigned rec[KPT];
    int bkt[KPT];
#pragma unroll
    for (int k = 0; k < KPT; k++) {
        int q = tid + k * 512;
        if (q < cnt) {
            int e = e0 + q;
            int d = dst[e];
            bkt[k] = d >> BSH;
            rec[k] = (unsigned)src[e] | ((unsigned)et[e] << 17) |
                     ((unsigned)(d & (BNODES - 1)) << 24);
            atomicAdd(&s_pend[bkt[k]], 1);
        } else bkt[k] = -1;
    }
    __syncthreads();
    // scan of padded (roundup4) lengths: 49 lanes x 16 bins
    if (tid < 49) {
        int loc[16];
        int s = 0;
        int b0 = tid * 16;
#pragma unroll
        for (int k = 0; k < 16; k++) {
            int plen = (s_pend[b0 + k] + 3) & ~3;
            loc[k] = plen; s += plen;
        }
        int inc = s;
#pragma unroll
        for (int off = 1; off < 64; off <<= 1) {
            int u = __shfl_up(inc, off);
            if (tid >= off) inc += u;
        }
        int run = inc - s;
#pragma unroll
        for (int k = 0; k < 16; k++) {
            s_cur[b0 + k] = run;
            run += loc[k];
            s_pend[b0 + k] = run;     // padded end = next start (monotone)
        }
    }
    __syncthreads();
    int T = s_pend[NB2 - 1];          // total padded slots this chunk
    // reservation (4-aligned) + overflow cleanup
    for (int b = tid; b < NB2; b += 512) {
        int st = s_cur[b];
        int plen = s_pend[b] - st;
        if (plen > 0) {
            int gb = atomicAdd(&gcount[b], plen);
            if (gb + plen <= CAPB) {
                s_off[b] = gb - st;   // multiple of 4
            } else {                  // overflow: drop run, keep region clean
                s_off[b] = 0x40000000;
                unsigned* reg = regions + (size_t)b * CAPB;
                for (int j = min(gb, CAPB); j < CAPB; j++) reg[j] = SENT;
            }
        } else s_off[b] = 0x40000000;
    }
    // sentinel pre-fill of the padded LDS image
    for (int i = tid; i < T; i += 512) s_pack[i] = SENT;
    __syncthreads();
    // place from regs
#pragma unroll
    for (int k = 0; k < KPT; k++) {
        if (bkt[k] >= 0) {
            int p = atomicAdd(&s_cur[bkt[k]], 1);
            s_pack[p] = rec[k];
        }
    }
    __syncthreads();
    // coalesced writeout: each aligned 4-slot group is within one run
    int nv = T >> 2;
    for (int i4 = tid; i4 < nv; i4 += 512) {
        int i = i4 << 2;
        int lo = 0, hi = NB2 - 1;     // first b with s_pend[b] > i
        while (lo < hi) {
            int mid = (lo + hi) >> 1;
            if (s_pend[mid] > i) hi = mid; else lo = mid + 1;
        }
        int loc = s_off[lo] + i;
        if (loc < CAPB) {
            uint4 v = make_uint4(s_pack[i], s_pack[i + 1],
                                 s_pack[i + 2], s_pack[i + 3]);
            *(uint4*)(regions + (size_t)lo * CAPB + loc) = v;
        }
    }
}

// ---------- K2: hist + FUSED LAYER 1 via LDS scatter-accumulate ----------
// reads region (uint4, sentinel-filtered) ONCE; u8 (dL,rel) hist; L1 msg
// accumulated straight from regs into acc[dL*7+j]; hist persisted for l3.
__launch_bounds__(512)
__global__ void sortb_l1_k(const int* __restrict__ gcount,
                           const unsigned* __restrict__ regions,
                           unsigned* __restrict__ ghist,
                           const float4* __restrict__ x4, const float* __restrict__ W,
                           const float* __restrict__ root, const float* __restrict__ bias,
                           float4* __restrict__ h1p, int N) {
    __shared__ unsigned hist8w[HWORDS];            // 11520 B
    __shared__ float4 w4[NREL * 2];                // 2880 B
    __shared__ float acc[BNODES * 7];              // 3584 B (stride 7: all banks)
    int tid = threadIdx.x, b = blockIdx.x;
    for (int i = tid; i < HWORDS; i += 512) hist8w[i] = 0u;
    for (int i = tid; i < BNODES * 7; i += 512) acc[i] = 0.0f;
    for (int i = tid; i < NREL * 2; i += 512) {
        int r = i >> 1;
        w4[i] = (i & 1) ? make_float4(W[r * 6 + 4], W[r * 6 + 5], 0.f, 0.f)
                        : make_float4(W[r * 6], W[r * 6 + 1], W[r * 6 + 2], W[r * 6 + 3]);
    }
    __syncthreads();
    int fill = gcount[b];
    if (fill > CAPB) fill = CAPB;
    const uint4* reg4 = (const uint4*)(regions + (size_t)b * CAPB);
    int nv = fill >> 2;               // fill is a multiple of 4
    uint4 rec4[NV4];
#pragma unroll
    for (int k = 0; k < NV4; k++) {
        int i4 = tid + k * 512;
        rec4[k] = (i4 < nv) ? reg4[i4] : make_uint4(SENT, SENT, SENT, SENT);
    }
#define HIST1(P) if ((P) != SENT) { \
        unsigned bi_ = ((P) >> 24) * 90u + (((P) >> 17) & 127u); \
        atomicAdd(&hist8w[bi_ >> 2], 1u << ((bi_ & 3) << 3)); }
#pragma unroll
    for (int k = 0; k < NV4; k++) {
        HIST1(rec4[k].x); HIST1(rec4[k].y); HIST1(rec4[k].z); HIST1(rec4[k].w);
    }
    __syncthreads();
    // L1 accumulate directly from regs (mean via per-record cnt lookup)
    const unsigned char* h8 = (const unsigned char*)hist8w;
#define L1ACC(P) if ((P) != SENT) { \
        unsigned dL_ = (P) >> 24, rel_ = ((P) >> 17) & 127u; \
        float r_ = __builtin_amdgcn_rcpf((float)h8[dL_ * 90 + rel_]); \
        float4 xv_ = x4[(P) & 0x1FFFFu]; \
        float4 wa_ = w4[rel_ * 2u], wb_ = w4[rel_ * 2u + 1u]; \
        float x0_ = xv_.x * r_, x1_ = xv_.y * r_, x2_ = xv_.z * r_; \
        float* a_ = &acc[dL_ * 7u]; \
        atomicAdd(a_ + 0, x0_ * wa_.x); atomicAdd(a_ + 1, x0_ * wa_.y); \
        atomicAdd(a_ + 2, x1_ * wa_.z); atomicAdd(a_ + 3, x1_ * wa_.w); \
        atomicAdd(a_ + 4, x2_ * wb_.x); atomicAdd(a_ + 5, x2_ * wb_.y); }
#pragma unroll
    for (int k = 0; k < NV4; k++) {
        L1ACC(rec4[k].x); L1ACC(rec4[k].y); L1ACC(rec4[k].z); L1ACC(rec4[k].w);
    }
    // persist counts for l3 (coalesced; independent of acc)
    unsigned* gh = ghist + (size_t)b * HWORDS;
    for (int i = tid; i < HWORDS; i += 512) gh[i] = hist8w[i];
    __syncthreads();
    if (tid < BNODES) {
        int d = (b << BSH) + tid;
        if (d < N) {
            float4 xv = x4[d];
            float o[6];
#pragma unroll
            for (int j = 0; j < 6; j++)
                o[j] = frelu(acc[tid * 7 + j] + xv.x * root[j] + xv.y * root[6 + j] +
                             xv.z * root[12 + j] + bias[j]);
            h1p[d * 2]     = make_float4(o[0], o[1], o[2], o[3]);
            h1p[d * 2 + 1] = make_float4(o[4], o[5], 0.0f, 0.0f);
        }
    }
}

// ---------- L2: bucket-block, sum aggr via LDS scatter-accumulate ----------
__launch_bounds__(512)
__global__ void l2_g(const int* __restrict__ gcount, const unsigned* __restrict__ regions,
                     const float4* __restrict__ h1p, const float* __restrict__ W,
                     const float* __restrict__ root, const float* __restrict__ bias,
                     float4* __restrict__ h2p, int N) {
    __shared__ float4 w4[NREL * 2];                // 2880 B
    __shared__ float acc[BNODES * 5];              // 2560 B (stride 5: all banks)
    int tid = threadIdx.x, b = blockIdx.x;
    for (int i = tid; i < BNODES * 5; i += 512) acc[i] = 0.0f;
    for (int i = tid; i < NREL * 2; i += 512) {
        int r = i >> 1;
        w4[i] = (i & 1) ? make_float4(W[r * 6 + 4], W[r * 6 + 5], 0.f, 0.f)
                        : make_float4(W[r * 6], W[r * 6 + 1], W[r * 6 + 2], W[r * 6 + 3]);
    }
    __syncthreads();
    int fill = gcount[b];
    if (fill > CAPB) fill = CAPB;
    const uint4* reg4 = (const uint4*)(regions + (size_t)b * CAPB);
    int nv = fill >> 2;
#define L2ACC(P) if ((P) != SENT) { \
        unsigned s_ = (P) & 0x1FFFFu, dL_ = (P) >> 24; \
        unsigned rel2_ = (((P) >> 17) & 127u) * 2u; \
        float4 ha_ = h1p[2 * s_], hb_ = h1p[2 * s_ + 1]; \
        float4 wa_ = w4[rel2_], wb_ = w4[rel2_ + 1]; \
        float* a_ = &acc[dL_ * 5u]; \
        atomicAdd(a_ + 0, ha_.x * wa_.x + ha_.y * wa_.y); \
        atomicAdd(a_ + 1, ha_.z * wa_.z + ha_.w * wa_.w); \
        atomicAdd(a_ + 2, hb_.x * wb_.x + hb_.y * wb_.y); }
#pragma unroll
    for (int k = 0; k < NV4; k++) {
        int i4 = tid + k * 512;
        uint4 v = (i4 < nv) ? reg4[i4] : make_uint4(SENT, SENT, SENT, SENT);
        L2ACC(v.x); L2ACC(v.y); L2ACC(v.z); L2ACC(v.w);
    }
    __syncthreads();
    if (tid < BNODES) {
        int d = (b << BSH) + tid;
        if (d < N) {
            float4 ha = h1p[2 * d], hb = h1p[2 * d + 1];
            float hv[6] = {ha.x, ha.y, ha.z, ha.w, hb.x, hb.y};
            float o[3];
#pragma unroll
            for (int j = 0; j < 3; j++) {
                float v = acc[tid * 5 + j] + bias[j];
#pragma unroll
                for (int k = 0; k < 6; k++) v += hv[k] * root[k * 3 + j];
                o[j] = frelu(v);
            }
            h2p[d] = make_float4(o[0], o[1], o[2], 0.0f);
        }
    }
}

// ---------- L3: bucket-block, mean via persisted hist, fused node + pool ----------
__launch_bounds__(512)
__global__ void l3_g(const int* __restrict__ gcount, const unsigned* __restrict__ regions,
                     const unsigned* __restrict__ ghist,
                     const float4* __restrict__ h2p, const float* __restrict__ W,
                     const float* __restrict__ root, const float* __restrict__ bias,
                     const int* __restrict__ batch, float* __restrict__ partials, int N) {
    __shared__ unsigned hist8w[HWORDS];            // 11520 B
    __shared__ float4 w4[NREL * 2];                // 2880 B
    __shared__ float acc[BNODES * 7];              // 3584 B
    __shared__ float redsm[BNODES][8];             // 4096 B
    int tid = threadIdx.x, b = blockIdx.x;
    const unsigned* gh = ghist + (size_t)b * HWORDS;
    for (int i = tid; i < HWORDS; i += 512) hist8w[i] = gh[i];
    for (int i = tid; i < BNODES * 7; i += 512) acc[i] = 0.0f;
    for (int i = tid; i < NREL * 2; i += 512) {
        int r = i >> 1;
        w4[i] = (i & 1) ? make_float4(W[r * 6 + 4], W[r * 6 + 5], 0.f, 0.f)
                        : make_float4(W[r * 6], W[r * 6 + 1], W[r * 6 + 2], W[r * 6 + 3]);
    }
    __syncthreads();
    int fill = gcount[b];
    if (fill > CAPB) fill = CAPB;
    const uint4* reg4 = (const uint4*)(regions + (size_t)b * CAPB);
    int nv = fill >> 2;
    const unsigned char* h8 = (const unsigned char*)hist8w;
#define L3ACC(P) if ((P) != SENT) { \
        unsigned dL_ = (P) >> 24, rel_ = ((P) >> 17) & 127u; \
        float r_ = __builtin_amdgcn_rcpf((float)h8[dL_ * 90 + rel_]); \
        float4 xv_ = h2p[(P) & 0x1FFFFu]; \
        float4 wa_ = w4[rel_ * 2u], wb_ = w4[rel_ * 2u + 1u]; \
        float x0_ = xv_.x * r_, x1_ = xv_.y * r_, x2_ = xv_.z * r_; \
        float* a_ = &acc[dL_ * 7u]; \
        atomicAdd(a_ + 0, x0_ * wa_.x); atomicAdd(a_ + 1, x0_ * wa_.y); \
        atomicAdd(a_ + 2, x1_ * wa_.z); atomicAdd(a_ + 3, x1_ * wa_.w); \
        atomicAdd(a_ + 4, x2_ * wb_.x); atomicAdd(a_ + 5, x2_ * wb_.y); }
#pragma unroll
    for (int k = 0; k < NV4; k++) {
        int i4 = tid + k * 512;
        uint4 v = (i4 < nv) ? reg4[i4] : make_uint4(SENT, SENT, SENT, SENT);
        L3ACC(v.x); L3ACC(v.y); L3ACC(v.z); L3ACC(v.w);
    }
    __syncthreads();
    if (tid < BNODES) {
        int d = (b << BSH) + tid;
        float v[7] = {0, 0, 0, 0, 0, 0, 0};
        if (d < N && batch[d] == 0) {
            float4 xv = h2p[d];
#pragma unroll
            for (int j = 0; j < 6; j++)
                v[j] = frelu(acc[tid * 7 + j] + xv.x * root[j] + xv.y * root[6 + j] +
                             xv.z * root[12 + j] + bias[j]);
            v[6] = 1.0f;
        }
#pragma unroll
        for (int k = 0; k < 7; k++) redsm[tid][k] = v[k];
    }
    __syncthreads();
    if (tid < 7) {
        float t = 0;
        for (int g = 0; g < BNODES; g++) t += redsm[g][tid];
        partials[(size_t)b * 8 + tid] = t;
    }
}

// ---------- finalize ----------
__global__ void pool_finalize(const float* __restrict__ partials, int nb,
                              float* __restrict__ out) {
    float v[7] = {0, 0, 0, 0, 0, 0, 0};
    for (int b = threadIdx.x; b < nb; b += blockDim.x) {
#pragma unroll
        for (int k = 0; k < 7; k++) v[k] += partials[(size_t)b * 8 + k];
    }
#pragma unroll
    for (int off = 32; off > 0; off >>= 1) {
#pragma unroll
        for (int k = 0; k < 7; k++) v[k] += __shfl_down(v[k], off);
    }
    __shared__ float sm[16][8];
    int wv = threadIdx.x >> 6, lane = threadIdx.x & 63;
    if (lane == 0) {
#pragma unroll
        for (int k = 0; k < 7; k++) sm[wv][k] = v[k];
    }
    __syncthreads();
    if (threadIdx.x == 0) {
        float t[7] = {0, 0, 0, 0, 0, 0, 0};
        int nw = blockDim.x >> 6;
        for (int q = 0; q < nw; q++) {
#pragma unroll
            for (int k = 0; k < 7; k++) t[k] += sm[q][k];
        }
        float c = t[6] < 1.0f ? 1.0f : t[6];
        float p[6], m = -1e30f;
#pragma unroll
        for (int j = 0; j < 6; j++) { p[j] = t[j] / c; m = fmaxf(m, p[j]); }
        float s = 0.0f;
#pragma unroll
        for (int j = 0; j < 6; j++) s += expf(p[j] - m);
        float lse = m + logf(s);
#pragma unroll
        for (int j = 0; j < 6; j++) out[j] = p[j] - lse;
    }
}

extern "C" void kernel_launch(void* const* d_in, const int* in_sizes, int n_in,
                              void* d_out, int out_size, void* d_ws, size_t ws_size,
                              hipStream_t stream) {
    const float* x     = (const float*)d_in[0];
    const int*   ei    = (const int*)d_in[1];
    const int*   batch = (const int*)d_in[2];
    const int*   etype = (const int*)d_in[3];
    const float* W1    = (const float*)d_in[4];
    const float* root1 = (const float*)d_in[5];
    const float* b1    = (const float*)d_in[6];
    const float* W2    = (const float*)d_in[7];
    const float* root2 = (const float*)d_in[8];
    const float* b2    = (const float*)d_in[9];
    const float* W3    = (const float*)d_in[10];
    const float* root3 = (const float*)d_in[11];
    const float* b3    = (const float*)d_in[12];

    const int N = in_sizes[0] / 3;
    const int E = in_sizes[1] / 2;
    const int* src = ei;
    const int* dst = ei + E;
    const int gG = (E + GCH - 1) / GCH;        // chunks (736 at E=6.4M)
    const int NBUCK = (N + BNODES - 1) >> BSH; // 782

    char* ws = (char*)d_ws;
    size_t off = 0;
    auto alloc = [&](size_t bytes) -> void* {
        void* p = ws + off;
        off += (bytes + 255) & ~(size_t)255;
        return p;
    };
    int*      gcount  = (int*)     alloc(NBINS * sizeof(int));                 // zeroed
    size_t zero_bytes = off;
    unsigned* regions = (unsigned*)alloc((size_t)NBUCK * CAPB * sizeof(unsigned)); // 32.8MB
    unsigned* ghist   = (unsigned*)alloc((size_t)NBUCK * HWORDS * sizeof(unsigned)); // 9.0MB
    float4*   x4      = (float4*)  alloc((size_t)N * sizeof(float4));          // 1.6MB
    float4*   h1p     = (float4*)  alloc((size_t)N * 2 * sizeof(float4));      // 3.2MB
    float4*   h2p     = (float4*)  alloc((size_t)N * sizeof(float4));          // 1.6MB
    float*    partials = (float*)  alloc((size_t)NBUCK * 8 * sizeof(float));
    // total ~48.5MB

    hipMemsetAsync(d_ws, 0, zero_bytes, stream);

    const int gNp = (N + 511) / 512;

    group_k<<<gNp + gG, 512, 0, stream>>>(x, x4, N, gNp, src, dst, etype,
                                          gcount, regions, E);
    sortb_l1_k<<<NBUCK, 512, 0, stream>>>(gcount, regions, ghist,
                                          x4, W1, root1, b1, h1p, N);
    l2_g<<<NBUCK, 512, 0, stream>>>(gcount, regions, h1p, W2, root2, b2, h2p, N);
    l3_g<<<NBUCK, 512, 0, stream>>>(gcount, regions, ghist, h2p, W3, root3, b3,
                                    batch, partials, N);
    pool_finalize<<<1, 1024, 0, stream>>>(partials, NBUCK, (float*)d_out);
}

// Round 10
// 281.011 us; speedup vs baseline: 2.9202x; 2.9202x over previous
//
#include <hip/hip_runtime.h>

// RGCN R20 (resubmit; round-9 bench was a broker/container failure, same as
// round 0): revert R19 (scatter-accumulate: LDS atomic RMW ~3-4cy/op, 7/edge
// = 268us, 10x worse than modeled) back to R18's sort structure, plus
// HALF-BUCKET sortb split: grid 2x782, each block sorts 64 of its bucket's
// 128 dsts. LDS 52->28.4KB (5 blk/CU resident, 6.1 of work) so the 8-phase
// pipeline's barrier stalls interleave across blocks; sorted halves land at
// disjoint fixed offsets (h*CAPB/2) -- rowseg is absolute so gaps are never
// read. Cost: bucket region read twice (+~3us BW).

#define NREL   90
#define BSH    7
#define BNODES 128       // nodes per bucket
#define NBINS  1024      // gcount table size
#define NB2    784       // scan bins (49 lanes x 16); buckets <= 782
#define GCH    8704      // edges per chunk = 512*17
#define KPT    17        // edges per thread in group_k
#define SPK    11056     // s_pack slots >= 8704 + 782*3 = 11050 hard max
#define CAPB   10496     // per-bucket region capacity; fill mean 9300 + 12s
#define NV4    6         // ceil(CAPB/4/512) uint4 loads per thread in sortb
#define HBN    64        // dsts per sortb half-block
#define HALF   (CAPB / 2)   // 5248: sorted-half region offset
#define STAGEH 4800      // half stage capacity; valid mean 4096 + 11s
#define LPD    16        // dsts per block in layer kernels (16 lanes each)
#define SENT   0xFFFFFFFFu

__device__ __forceinline__ float frelu(float v) { return v > 0.0f ? v : 0.0f; }

// ---------- K1: fused pad-x + single-read grouping, padded reservation ----------
// record = src | rel<<17 | dstLocal<<24 ; sentinel unreachable (rel <= 89).
__launch_bounds__(512)
__global__ void group_k(const float* __restrict__ x, float4* __restrict__ x4,
                        int N, int gNp,
                        const int* __restrict__ src, const int* __restrict__ dst,
                        const int* __restrict__ et, int* __restrict__ gcount,
                        unsigned* __restrict__ regions, int E) {
    int tid = threadIdx.x;
    if (blockIdx.x < gNp) {           // pad role
        int i = blockIdx.x * 512 + tid;
        if (i < N) x4[i] = make_float4(x[3 * i], x[3 * i + 1], x[3 * i + 2], 0.0f);
        return;
    }
    __shared__ int s_cur[NB2];        // 4-aligned starts -> place cursor
    __shared__ int s_pend[NB2];       // hist, then padded end (next start)
    __shared__ int s_off[NB2];        // reserved_base - start (multiple of 4)
    __shared__ unsigned s_pack[SPK];  // 44224 B -> total 53632 B (3 blk/CU)
    int chunk = blockIdx.x - gNp;
    int e0 = chunk * GCH;
    int cnt = min(GCH, E - e0);
    for (int i = tid; i < NB2; i += 512) s_pend[i] = 0;
    __syncthreads();
    // single global read: pack records into VGPRs, hist from regs
    unsigned rec[KPT];
    int bkt[KPT];
#pragma unroll
    for (int k = 0; k < KPT; k++) {
        int q = tid + k * 512;
        if (q < cnt) {
            int e = e0 + q;
            int d = dst[e];
            bkt[k] = d >> BSH;
            rec[k] = (unsigned)src[e] | ((unsigned)et[e] << 17) |
                     ((unsigned)(d & (BNODES - 1)) << 24);
            atomicAdd(&s_pend[bkt[k]], 1);
        } else bkt[k] = -1;
    }
    __syncthreads();
    // scan of padded (roundup4) lengths: 49 lanes x 16 bins
    if (tid < 49) {
        int loc[16];
        int s = 0;
        int b0 = tid * 16;
#pragma unroll
        for (int k = 0; k < 16; k++) {
            int plen = (s_pend[b0 + k] + 3) & ~3;
            loc[k] = plen; s += plen;
        }
        int inc = s;
#pragma unroll
        for (int off = 1; off < 64; off <<= 1) {
            int u = __shfl_up(inc, off);
            if (tid >= off) inc += u;
        }
        int run = inc - s;
#pragma unroll
        for (int k = 0; k < 16; k++) {
            s_cur[b0 + k] = run;
            run += loc[k];
            s_pend[b0 + k] = run;     // padded end = next start (monotone)
        }
    }
    __syncthreads();
    int T = s_pend[NB2 - 1];          // total padded slots this chunk
    // reservation (4-aligned) + overflow cleanup
    for (int b = tid; b < NB2; b += 512) {
        int st = s_cur[b];
        int plen = s_pend[b] - st;
        if (plen > 0) {
            int gb = atomicAdd(&gcount[b], plen);
            if (gb + plen <= CAPB) {
                s_off[b] = gb - st;   // multiple of 4
            } else {                  // overflow: drop run, keep region clean
                s_off[b] = 0x40000000;
                unsigned* reg = regions + (size_t)b * CAPB;
                for (int j = min(gb, CAPB); j < CAPB; j++) reg[j] = SENT;
            }
        } else s_off[b] = 0x40000000;
    }
    // sentinel pre-fill of the padded LDS image
    for (int i = tid; i < T; i += 512) s_pack[i] = SENT;
    __syncthreads();
    // place from regs
#pragma unroll
    for (int k = 0; k < KPT; k++) {
        if (bkt[k] >= 0) {
            int p = atomicAdd(&s_cur[bkt[k]], 1);
            s_pack[p] = rec[k];
        }
    }
    __syncthreads();
    // coalesced writeout: each aligned 4-slot group is within one run
    int nv = T >> 2;
    for (int i4 = tid; i4 < nv; i4 += 512) {
        int i = i4 << 2;
        int lo = 0, hi = NB2 - 1;     // first b with s_pend[b] > i
        while (lo < hi) {
            int mid = (lo + hi) >> 1;
            if (s_pend[mid] > i) hi = mid; else lo = mid + 1;
        }
        int loc = s_off[lo] + i;
        if (loc < CAPB) {
            uint4 v = make_uint4(s_pack[i], s_pack[i + 1],
                                 s_pack[i + 2], s_pack[i + 3]);
            *(uint4*)(regions + (size_t)lo * CAPB + loc) = v;
        }
    }
}

// ---------- K2: HALF-BUCKET (dst,rel) counting sort + FUSED LAYER 1 ----------
// block (b,h): reads bucket b's region, keeps records with dL bit6 == h,
// sorts 64 dsts, computes L1, writes sorted cnt-packed records linearly at
// region offset h*HALF. rowseg carries absolute indices.
__launch_bounds__(512)
__global__ void sortb_l1_k(const int* __restrict__ gcount, unsigned* regions,
                           int2* __restrict__ rowseg,
                           const float4* __restrict__ x4, const float* __restrict__ W,
                           const float* __restrict__ root, const float* __restrict__ bias,
                           float4* __restrict__ h1p, int N) {
    __shared__ unsigned stage32[STAGEH];           // 19200 B
    __shared__ unsigned hist8w[HBN * 90 / 4];      // 5760 B
    __shared__ int hh[HBN], base_[HBN];            // 512 B
    __shared__ float4 w4[NREL * 2];                // 2880 B -> ~28.4 KB (5 blk/CU)
    int tid = threadIdx.x;
    int b = blockIdx.x >> 1;
    unsigned hbit = ((unsigned)blockIdx.x & 1u) << 6;
    for (int i = tid; i < HBN * 90 / 4; i += 512) hist8w[i] = 0u;
    for (int i = tid; i < NREL * 2; i += 512) {
        int r = i >> 1;
        w4[i] = (i & 1) ? make_float4(W[r * 6 + 4], W[r * 6 + 5], 0.f, 0.f)
                        : make_float4(W[r * 6], W[r * 6 + 1], W[r * 6 + 2], W[r * 6 + 3]);
    }
    __syncthreads();
    int fill = gcount[b];
    if (fill > CAPB) fill = CAPB;
    const uint4* reg4 = (const uint4*)(regions + (size_t)b * CAPB);
    int nv = fill >> 2;               // fill is a multiple of 4
    // phase A: all 6 uint4 loads issued first (6-deep MLP), then u8 hist of
    // this half's records only
    uint4 rec4[NV4];
#pragma unroll
    for (int k = 0; k < NV4; k++) {
        int i4 = tid + k * 512;
        rec4[k] = (i4 < nv) ? reg4[i4] : make_uint4(SENT, SENT, SENT, SENT);
    }
#define HIST1(P) if ((P) != SENT && (((P) >> 24) & 64u) == hbit) { \
        unsigned bi_ = (((P) >> 24) & 63u) * 90u + (((P) >> 17) & 127u); \
        atomicAdd(&hist8w[bi_ >> 2], 1u << ((bi_ & 3) << 3)); }
#pragma unroll
    for (int k = 0; k < NV4; k++) {
        HIST1(rec4[k].x); HIST1(rec4[k].y); HIST1(rec4[k].z); HIST1(rec4[k].w);
    }
    __syncthreads();
    // in-place rel-prefix conversion (64 disjoint 90-byte rows) FUSED with the
    // 64-bin dst scan (wave 0, shfl)
    unsigned char* h8w = (unsigned char*)hist8w;
    if (tid < HBN) {
        unsigned run = 0;
        int rbase = tid * 90;
        for (int k = 0; k < 90; k++) {
            unsigned c = h8w[rbase + k];
            h8w[rbase + k] = (unsigned char)run;
            run += c;
        }
        hh[tid] = (int)run;
        int s = (int)run;
        int inc = s;
#pragma unroll
        for (int off = 1; off < 64; off <<= 1) {
            int u = __shfl_up(inc, off);
            if (tid >= off) inc += u;
        }
        base_[tid] = inc - s;
    }
    __syncthreads();
    int cntv = base_[HBN - 1] + hh[HBN - 1];   // valid records this half
    if (cntv > STAGEH) cntv = STAGEH;          // safety clamp
    int segbase = b * CAPB + (int)(hbit >> 6) * HALF;
    if (tid < HBN) {
        int d = (b << BSH) + (int)hbit + tid;
        if (d < N) {
            int beg = base_[tid];
            int end = beg + hh[tid];
            if (beg > cntv) beg = cntv;
            if (end > cntv) end = cntv;
            rowseg[d] = make_int2(segbase + beg, segbase + end);
        }
    }
    // phase B: place this half's records rel-sorted via byte-prefix atomics
#define PLACE1(P) if ((P) != SENT && (((P) >> 24) & 64u) == hbit) { \
        unsigned dL_ = ((P) >> 24) & 63u; \
        unsigned bi_ = dL_ * 90u + (((P) >> 17) & 127u); \
        unsigned old_ = atomicAdd(&hist8w[bi_ >> 2], 1u << ((bi_ & 3) << 3)); \
        int pos_ = base_[dL_] + (int)((old_ >> ((bi_ & 3) << 3)) & 0xFFu); \
        if (pos_ < STAGEH) stage32[pos_] = (P); }
#pragma unroll
    for (int k = 0; k < NV4; k++) {
        PLACE1(rec4[k].x); PLACE1(rec4[k].y); PLACE1(rec4[k].z); PLACE1(rec4[k].w);
    }
    __syncthreads();
    // phase C (fused L1): 32 groups of 16 lanes, 2 dsts each; hist8w bytes are
    // inclusive prefixes -> c = byte diff; cnt-packed record back to stage32
    const unsigned char* h8 = (const unsigned char*)hist8w;
    int grp = tid >> 4, l16 = tid & 15;
#pragma unroll
    for (int rd = 0; rd < 2; rd++) {
        int dL = grp + rd * 32;
        int segb = base_[dL];
        int sege = segb + hh[dL];
        if (sege > cntv) sege = cntv;
        float a0 = 0, a1 = 0, a2 = 0, a3 = 0, a4 = 0, a5 = 0;
        for (int q = segb + l16; q < sege; q += 16) {
            unsigned p = stage32[q];
            unsigned rel = (p >> 17) & 127u;
            unsigned bi = dL * 90u + rel;
            unsigned c = (unsigned)h8[bi] - (rel ? (unsigned)h8[bi - 1] : 0u);
            stage32[q] = (p & 0x00FFFFFFu) | (c << 24);
            float r = __builtin_amdgcn_rcpf((float)c);
            float4 xv = x4[p & 0x1FFFFu];
            unsigned rel2 = rel * 2u;
            float4 wa = w4[rel2], wb = w4[rel2 + 1];
            float x0 = xv.x * r, x1 = xv.y * r, x2 = xv.z * r;
            a0 += x0 * wa.x; a1 += x0 * wa.y;
            a2 += x1 * wa.z; a3 += x1 * wa.w;
            a4 += x2 * wb.x; a5 += x2 * wb.y;
        }
#pragma unroll
        for (int off = 8; off > 0; off >>= 1) {
            a0 += __shfl_down(a0, off); a1 += __shfl_down(a1, off); a2 += __shfl_down(a2, off);
            a3 += __shfl_down(a3, off); a4 += __shfl_down(a4, off); a5 += __shfl_down(a5, off);
        }
        if (l16 == 0) {
            int d = (b << BSH) + (int)hbit + dL;
            if (d < N) {
                float4 xv = x4[d];
                float o[6] = {a0, a1, a2, a3, a4, a5};
#pragma unroll
                for (int j = 0; j < 6; j++)
                    o[j] = frelu(o[j] + xv.x * root[j] + xv.y * root[6 + j] +
                                 xv.z * root[12 + j] + bias[j]);
                h1p[d * 2]     = make_float4(o[0], o[1], o[2], o[3]);
                h1p[d * 2 + 1] = make_float4(o[4], o[5], 0.0f, 0.0f);
            }
        }
    }
    __syncthreads();
    // linear coalesced writeout of this half's sorted, cnt-packed records
    unsigned* regw = regions + (size_t)segbase;
    int nv2 = (cntv + 3) >> 2;
    for (int i4 = tid; i4 < nv2; i4 += 512) {
        int i = i4 << 2;
        uint4 v;
        v.x = stage32[i];
        v.y = (i + 1 < cntv) ? stage32[i + 1] : SENT;
        v.z = (i + 2 < cntv) ? stage32[i + 2] : SENT;
        v.w = (i + 3 < cntv) ? stage32[i + 3] : SENT;
        *(uint4*)(regw + i) = v;
    }
}

// ---------- L2: predicated 4-unroll, 16 lanes/dst, both components/lane ----------
__launch_bounds__(256)
__global__ void l2_g(const int2* __restrict__ rowseg, const unsigned* __restrict__ sorted,
                     const float4* __restrict__ h1p, const float* __restrict__ W,
                     const float* __restrict__ root, const float* __restrict__ bias,
                     float4* __restrict__ h2p, int N) {
    __shared__ float4 w4[NREL * 2];
    for (int i = threadIdx.x; i < NREL * 2; i += 256) {
        int r = i >> 1;
        w4[i] = (i & 1) ? make_float4(W[r * 6 + 4], W[r * 6 + 5], 0.f, 0.f)
                        : make_float4(W[r * 6], W[r * 6 + 1], W[r * 6 + 2], W[r * 6 + 3]);
    }
    __syncthreads();
    int grp = threadIdx.x >> 4, l16 = threadIdx.x & 15;
    int d = blockIdx.x * LPD + grp;
    if (d >= N) return;
    int2 sg = rowseg[d];
    int beg = sg.x, end = sg.y;
    float a0 = 0, a1 = 0, a2 = 0;
    for (int i0 = beg + l16; i0 < end; i0 += 64) {
        unsigned p[4];
        float sc[4];
        float4 ha[4], hb[4];
#pragma unroll
        for (int k = 0; k < 4; k++) {       // predicated record loads
            int i = i0 + k * 16;
            int ic = i < end ? i : end - 1;
            p[k] = sorted[ic];
            sc[k] = i < end ? 1.0f : 0.0f;
        }
#pragma unroll
        for (int k = 0; k < 4; k++) {       // 8 independent gathers in flight
            unsigned s = p[k] & 0x1FFFFu;
            ha[k] = h1p[2 * s]; hb[k] = h1p[2 * s + 1];
        }
#pragma unroll
        for (int k = 0; k < 4; k++) {
            unsigned rel2 = ((p[k] >> 17) & 127u) * 2u;
            float4 wa = w4[rel2], wb = w4[rel2 + 1];
            float m0 = ha[k].x * wa.x + ha[k].y * wa.y;
            float m1 = ha[k].z * wa.z + ha[k].w * wa.w;
            float m2 = hb[k].x * wb.x + hb[k].y * wb.y;
            a0 += sc[k] * m0; a1 += sc[k] * m1; a2 += sc[k] * m2;
        }
    }
#pragma unroll
    for (int off = 8; off > 0; off >>= 1) {
        a0 += __shfl_down(a0, off); a1 += __shfl_down(a1, off); a2 += __shfl_down(a2, off);
    }
    if (l16 == 0) {
        float4 ha = h1p[2 * d], hb = h1p[2 * d + 1];
        float hv[6] = {ha.x, ha.y, ha.z, ha.w, hb.x, hb.y};
        float o[3] = {a0, a1, a2};
#pragma unroll
        for (int j = 0; j < 3; j++) {
            float v = o[j] + bias[j];
#pragma unroll
            for (int k = 0; k < 6; k++) v += hv[k] * root[k * 3 + j];
            o[j] = frelu(v);
        }
        h2p[d] = make_float4(o[0], o[1], o[2], 0.0f);
    }
}

// ---------- L3: predicated 4-unroll, mean via packed cnt, fused node + pool ----------
__launch_bounds__(256)
__global__ void l3_g(const int2* __restrict__ rowseg, const unsigned* __restrict__ sorted,
                     const float4* __restrict__ h2p, const float* __restrict__ W,
                     const float* __restrict__ root, const float* __restrict__ bias,
                     const int* __restrict__ batch, float* __restrict__ partials, int N) {
    __shared__ float4 w4[NREL * 2];
    __shared__ float redsm[LPD][8];
    for (int i = threadIdx.x; i < NREL * 2; i += 256) {
        int r = i >> 1;
        w4[i] = (i & 1) ? make_float4(W[r * 6 + 4], W[r * 6 + 5], 0.f, 0.f)
                        : make_float4(W[r * 6], W[r * 6 + 1], W[r * 6 + 2], W[r * 6 + 3]);
    }
    __syncthreads();
    int grp = threadIdx.x >> 4, l16 = threadIdx.x & 15;
    int d = blockIdx.x * LPD + grp;
    float a0 = 0, a1 = 0, a2 = 0, a3 = 0, a4 = 0, a5 = 0;
    if (d < N) {
        int2 sg = rowseg[d];
        int beg = sg.x, end = sg.y;
        for (int i0 = beg + l16; i0 < end; i0 += 64) {
            unsigned p[4];
            float sc[4];
            float4 xv[4];
#pragma unroll
            for (int k = 0; k < 4; k++) {   // predicated record loads
                int i = i0 + k * 16;
                int ic = i < end ? i : end - 1;
                p[k] = sorted[ic];
                sc[k] = i < end ? 1.0f : 0.0f;
            }
#pragma unroll
            for (int k = 0; k < 4; k++) xv[k] = h2p[p[k] & 0x1FFFFu];
#pragma unroll
            for (int k = 0; k < 4; k++) {
                // validity folds into the mean factor: zero r kills all 6 FMAs
                float r = sc[k] * __builtin_amdgcn_rcpf((float)(p[k] >> 24));
                unsigned rel2 = ((p[k] >> 17) & 127u) * 2u;
                float4 wa = w4[rel2], wb = w4[rel2 + 1];
                float x0 = xv[k].x * r, x1 = xv[k].y * r, x2 = xv[k].z * r;
                a0 += x0 * wa.x; a1 += x0 * wa.y;
                a2 += x1 * wa.z; a3 += x1 * wa.w;
                a4 += x2 * wb.x; a5 += x2 * wb.y;
            }
        }
    }
#pragma unroll
    for (int off = 8; off > 0; off >>= 1) {
        a0 += __shfl_down(a0, off); a1 += __shfl_down(a1, off); a2 += __shfl_down(a2, off);
        a3 += __shfl_down(a3, off); a4 += __shfl_down(a4, off); a5 += __shfl_down(a5, off);
    }
    if (l16 == 0) {
        float v[7] = {0, 0, 0, 0, 0, 0, 0};
        if (d < N && batch[d] == 0) {
            float4 xv = h2p[d];
            float o[6] = {a0, a1, a2, a3, a4, a5};
#pragma unroll
            for (int j = 0; j < 6; j++)
                v[j] = frelu(o[j] + xv.x * root[j] + xv.y * root[6 + j] +
                             xv.z * root[12 + j] + bias[j]);
            v[6] = 1.0f;
        }
#pragma unroll
        for (int k = 0; k < 7; k++) redsm[grp][k] = v[k];
    }
    __syncthreads();
    if (threadIdx.x < 7) {
        float t = 0;
#pragma unroll
        for (int g = 0; g < LPD; g++) t += redsm[g][threadIdx.x];
        partials[(size_t)blockIdx.x * 8 + threadIdx.x] = t;
    }
}

// ---------- finalize ----------
__global__ void pool_finalize(const float* __restrict__ partials, int nb,
                              float* __restrict__ out) {
    float v[7] = {0, 0, 0, 0, 0, 0, 0};
    for (int b = threadIdx.x; b < nb; b += blockDim.x) {
#pragma unroll
        for (int k = 0; k < 7; k++) v[k] += partials[(size_t)b * 8 + k];
    }
#pragma unroll
    for (int off = 32; off > 0; off >>= 1) {
#pragma unroll
        for (int k = 0; k < 7; k++) v[k] += __shfl_down(v[k], off);
    }
    __shared__ float sm[16][8];
    int wv = threadIdx.x >> 6, lane = threadIdx.x & 63;
    if (lane == 0) {
#pragma unroll
        for (int k = 0; k < 7; k++) sm[wv][k] = v[k];
    }
    __syncthreads();
    if (threadIdx.x == 0) {
        float t[7] = {0, 0, 0, 0, 0, 0, 0};
        int nw = blockDim.x >> 6;
        for (int q = 0; q < nw; q++) {
#pragma unroll
            for (int k = 0; k < 7; k++) t[k] += sm[q][k];
        }
        float c = t[6] < 1.0f ? 1.0f : t[6];
        float p[6], m = -1e30f;
#pragma unroll
        for (int j = 0; j < 6; j++) { p[j] = t[j] / c; m = fmaxf(m, p[j]); }
        float s = 0.0f;
#pragma unroll
        for (int j = 0; j < 6; j++) s += expf(p[j] - m);
        float lse = m + logf(s);
#pragma unroll
        for (int j = 0; j < 6; j++) out[j] = p[j] - lse;
    }
}

extern "C" void kernel_launch(void* const* d_in, const int* in_sizes, int n_in,
                              void* d_out, int out_size, void* d_ws, size_t ws_size,
                              hipStream_t stream) {
    const float* x     = (const float*)d_in[0];
    const int*   ei    = (const int*)d_in[1];
    const int*   batch = (const int*)d_in[2];
    const int*   etype = (const int*)d_in[3];
    const float* W1    = (const float*)d_in[4];
    const float* root1 = (const float*)d_in[5];
    const float* b1    = (const float*)d_in[6];
    const float* W2    = (const float*)d_in[7];
    const float* root2 = (const float*)d_in[8];
    const float* b2    = (const float*)d_in[9];
    const float* W3    = (const float*)d_in[10];
    const float* root3 = (const float*)d_in[11];
    const float* b3    = (const float*)d_in[12];

    const int N = in_sizes[0] / 3;
    const int E = in_sizes[1] / 2;
    const int* src = ei;
    const int* dst = ei + E;
    const int gG = (E + GCH - 1) / GCH;        // chunks (736 at E=6.4M)
    const int NBUCK = (N + BNODES - 1) >> BSH; // 782
    const int gL = (N + LPD - 1) / LPD;        // 6250

    char* ws = (char*)d_ws;
    size_t off = 0;
    auto alloc = [&](size_t bytes) -> void* {
        void* p = ws + off;
        off += (bytes + 255) & ~(size_t)255;
        return p;
    };
    int*      gcount  = (int*)     alloc(NBINS * sizeof(int));                 // zeroed
    size_t zero_bytes = off;
    unsigned* regions = (unsigned*)alloc((size_t)NBUCK * CAPB * sizeof(unsigned)); // 32.8MB
    int2*     rowseg  = (int2*)    alloc((size_t)N * sizeof(int2));            // 0.8MB
    float4*   x4      = (float4*)  alloc((size_t)N * sizeof(float4));          // 1.6MB
    float4*   h1p     = (float4*)  alloc((size_t)N * 2 * sizeof(float4));      // 3.2MB
    float4*   h2p     = (float4*)  alloc((size_t)N * sizeof(float4));          // 1.6MB
    float*    partials = (float*)  alloc((size_t)gL * 8 * sizeof(float));
    // total ~41MB

    hipMemsetAsync(d_ws, 0, zero_bytes, stream);

    const int gNp = (N + 511) / 512;

    group_k<<<gNp + gG, 512, 0, stream>>>(x, x4, N, gNp, src, dst, etype,
                                          gcount, regions, E);
    sortb_l1_k<<<NBUCK * 2, 512, 0, stream>>>(gcount, regions, rowseg,
                                              x4, W1, root1, b1, h1p, N);
    l2_g<<<gL, 256, 0, stream>>>(rowseg, regions, h1p, W2, root2, b2, h2p, N);
    l3_g<<<gL, 256, 0, stream>>>(rowseg, regions, h2p, W3, root3, b3, batch, partials, N);
    pool_finalize<<<1, 1024, 0, stream>>>(partials, gL, (float*)d_out);
}

// Round 11
// 273.332 us; speedup vs baseline: 3.0023x; 1.0281x over previous
//
#include <hip/hip_runtime.h>
#include <hip/hip_fp16.h>

// RGCN R21: (1) revert R20 half-split (counters moved as predicted --
// occupancy 31->58% -- but time identical: sortb is LDS-pipeline
// throughput-bound, not barrier-latency-bound; the split only added fetch);
// (2) h1 packed as 8xfp16 in ONE uint4 -> l2's two 16B gathers per edge
// become ONE (R16 established per-lane gather addressing, not lines, is the
// cost). Predicted absmax ~1e-4 (fp16 h1, errors average out in pooling).

#define NREL   90
#define BSH    7
#define BNODES 128       // nodes per bucket
#define NBINS  1024      // gcount table size
#define NB2    784       // scan bins (49 lanes x 16); buckets <= 782
#define GCH    8704      // edges per chunk = 512*17
#define KPT    17        // edges per thread in group_k
#define SPK    11056     // s_pack slots >= 8704 + 782*3 = 11050 hard max
#define CAPB   10496     // per-bucket region capacity; fill mean 9300 + 12s
#define NV4    6         // ceil(CAPB/4/512) uint4 loads per thread in sortb
#define STAGE  9088      // sortb stage capacity; valid cnt mean 8192 + 9.9s
#define LPD    16        // dsts per block in layer kernels (16 lanes each)
#define SENT   0xFFFFFFFFu

__device__ __forceinline__ float frelu(float v) { return v > 0.0f ? v : 0.0f; }

// ---------- K1: fused pad-x + single-read grouping, padded reservation ----------
// record = src | rel<<17 | dstLocal<<24 ; sentinel unreachable (rel <= 89).
__launch_bounds__(512)
__global__ void group_k(const float* __restrict__ x, float4* __restrict__ x4,
                        int N, int gNp,
                        const int* __restrict__ src, const int* __restrict__ dst,
                        const int* __restrict__ et, int* __restrict__ gcount,
                        unsigned* __restrict__ regions, int E) {
    int tid = threadIdx.x;
    if (blockIdx.x < gNp) {           // pad role
        int i = blockIdx.x * 512 + tid;
        if (i < N) x4[i] = make_float4(x[3 * i], x[3 * i + 1], x[3 * i + 2], 0.0f);
        return;
    }
    __shared__ int s_cur[NB2];        // 4-aligned starts -> place cursor
    __shared__ int s_pend[NB2];       // hist, then padded end (next start)
    __shared__ int s_off[NB2];        // reserved_base - start (multiple of 4)
    __shared__ unsigned s_pack[SPK];  // 44224 B -> total 53632 B (3 blk/CU)
    int chunk = blockIdx.x - gNp;
    int e0 = chunk * GCH;
    int cnt = min(GCH, E - e0);
    for (int i = tid; i < NB2; i += 512) s_pend[i] = 0;
    __syncthreads();
    // single global read: pack records into VGPRs, hist from regs
    unsigned rec[KPT];
    int bkt[KPT];
#pragma unroll
    for (int k = 0; k < KPT; k++) {
        int q = tid + k * 512;
        if (q < cnt) {
            int e = e0 + q;
            int d = dst[e];
            bkt[k] = d >> BSH;
            rec[k] = (unsigned)src[e] | ((unsigned)et[e] << 17) |
                     ((unsigned)(d & (BNODES - 1)) << 24);
            atomicAdd(&s_pend[bkt[k]], 1);
        } else bkt[k] = -1;
    }
    __syncthreads();
    // scan of padded (roundup4) lengths: 49 lanes x 16 bins
    if (tid < 49) {
        int loc[16];
        int s = 0;
        int b0 = tid * 16;
#pragma unroll
        for (int k = 0; k < 16; k++) {
            int plen = (s_pend[b0 + k] + 3) & ~3;
            loc[k] = plen; s += plen;
        }
        int inc = s;
#pragma unroll
        for (int off = 1; off < 64; off <<= 1) {
            int u = __shfl_up(inc, off);
            if (tid >= off) inc += u;
        }
        int run = inc - s;
#pragma unroll
        for (int k = 0; k < 16; k++) {
            s_cur[b0 + k] = run;
            run += loc[k];
            s_pend[b0 + k] = run;     // padded end = next start (monotone)
        }
    }
    __syncthreads();
    int T = s_pend[NB2 - 1];          // total padded slots this chunk
    // reservation (4-aligned) + overflow cleanup
    for (int b = tid; b < NB2; b += 512) {
        int st = s_cur[b];
        int plen = s_pend[b] - st;
        if (plen > 0) {
            int gb = atomicAdd(&gcount[b], plen);
            if (gb + plen <= CAPB) {
                s_off[b] = gb - st;   // multiple of 4
            } else {                  // overflow: drop run, keep region clean
                s_off[b] = 0x40000000;
                unsigned* reg = regions + (size_t)b * CAPB;
                for (int j = min(gb, CAPB); j < CAPB; j++) reg[j] = SENT;
            }
        } else s_off[b] = 0x40000000;
    }
    // sentinel pre-fill of the padded LDS image
    for (int i = tid; i < T; i += 512) s_pack[i] = SENT;
    __syncthreads();
    // place from regs
#pragma unroll
    for (int k = 0; k < KPT; k++) {
        if (bkt[k] >= 0) {
            int p = atomicAdd(&s_cur[bkt[k]], 1);
            s_pack[p] = rec[k];
        }
    }
    __syncthreads();
    // coalesced writeout: each aligned 4-slot group is within one run
    int nv = T >> 2;
    for (int i4 = tid; i4 < nv; i4 += 512) {
        int i = i4 << 2;
        int lo = 0, hi = NB2 - 1;     // first b with s_pend[b] > i
        while (lo < hi) {
            int mid = (lo + hi) >> 1;
            if (s_pend[mid] > i) hi = mid; else lo = mid + 1;
        }
        int loc = s_off[lo] + i;
        if (loc < CAPB) {
            uint4 v = make_uint4(s_pack[i], s_pack[i + 1],
                                 s_pack[i + 2], s_pack[i + 3]);
            *(uint4*)(regions + (size_t)lo * CAPB + loc) = v;
        }
    }
}

// ---------- K2: (dst,rel) counting sort + FUSED LAYER 1 (R18 structure) ----------
// reads region (uint4, sentinel-filtered), emits records sorted by (dst,rel)
// (src | rel<<17 | cnt<<24) via stage32 -> LINEAR uint4 writeout, rowseg,
// h1 packed as 8 fp16 in one uint4 (single-gather table for l2).
__launch_bounds__(512)
__global__ void sortb_l1_k(const int* __restrict__ gcount, unsigned* regions,
                           int2* __restrict__ rowseg,
                           const float4* __restrict__ x4, const float* __restrict__ W,
                           const float* __restrict__ root, const float* __restrict__ bias,
                           uint4* __restrict__ h1h, int N) {
    __shared__ unsigned stage32[STAGE];            // 36352 B
    __shared__ unsigned hist8w[BNODES * 90 / 4];   // 11520 B
    __shared__ int hh[BNODES], base_[BNODES];      // 1024 B
    __shared__ float4 w4[NREL * 2];                // 2880 B -> 51776 total
    int tid = threadIdx.x, b = blockIdx.x;
    for (int i = tid; i < BNODES * 90 / 4; i += 512) hist8w[i] = 0u;
    for (int i = tid; i < NREL * 2; i += 512) {
        int r = i >> 1;
        w4[i] = (i & 1) ? make_float4(W[r * 6 + 4], W[r * 6 + 5], 0.f, 0.f)
                        : make_float4(W[r * 6], W[r * 6 + 1], W[r * 6 + 2], W[r * 6 + 3]);
    }
    __syncthreads();
    int fill = gcount[b];
    if (fill > CAPB) fill = CAPB;
    const uint4* reg4 = (const uint4*)(regions + (size_t)b * CAPB);
    int nv = fill >> 2;               // fill is a multiple of 4
    // phase A: all 6 uint4 loads issued first (6-deep MLP), then u8 hist
    uint4 rec4[NV4];
#pragma unroll
    for (int k = 0; k < NV4; k++) {
        int i4 = tid + k * 512;
        rec4[k] = (i4 < nv) ? reg4[i4] : make_uint4(SENT, SENT, SENT, SENT);
    }
#define HIST1(P) if ((P) != SENT) { \
        unsigned bi_ = ((P) >> 24) * 90u + (((P) >> 17) & 127u); \
        atomicAdd(&hist8w[bi_ >> 2], 1u << ((bi_ & 3) << 3)); }
#pragma unroll
    for (int k = 0; k < NV4; k++) {
        HIST1(rec4[k].x); HIST1(rec4[k].y); HIST1(rec4[k].z); HIST1(rec4[k].w);
    }
    __syncthreads();
    // in-place rel-prefix conversion: 128 threads, one 90-byte dst row each
    unsigned char* h8w = (unsigned char*)hist8w;
    if (tid < BNODES) {
        unsigned run = 0;
        int rbase = tid * 90;
        for (int k = 0; k < 90; k++) {
            unsigned c = h8w[rbase + k];
            h8w[rbase + k] = (unsigned char)run;
            run += c;
        }
        hh[tid] = (int)run;
    }
    __syncthreads();
    if (tid < 64) {       // exclusive scan of 128 bins, 2/lane
        int c0 = hh[2 * tid], c1 = hh[2 * tid + 1];
        int s = c0 + c1;
        int inc = s;
#pragma unroll
        for (int off = 1; off < 64; off <<= 1) {
            int u = __shfl_up(inc, off);
            if (tid >= off) inc += u;
        }
        int run2 = inc - s;
        base_[2 * tid] = run2;
        base_[2 * tid + 1] = run2 + c0;
    }
    __syncthreads();
    int cntv = base_[BNODES - 1] + hh[BNODES - 1];   // total valid records
    if (cntv > STAGE) cntv = STAGE;                  // safety clamp
    if (tid < BNODES) {
        int d = (b << BSH) + tid;
        if (d < N) {
            int beg = base_[tid];
            int end = beg + hh[tid];
            if (beg > cntv) beg = cntv;
            if (end > cntv) end = cntv;
            rowseg[d] = make_int2(b * CAPB + beg, b * CAPB + end);
        }
    }
    // phase B: place records rel-sorted; byte atomic on prefix = in-dst slot
#define PLACE1(P) if ((P) != SENT) { \
        unsigned dL_ = (P) >> 24; \
        unsigned bi_ = dL_ * 90u + (((P) >> 17) & 127u); \
        unsigned old_ = atomicAdd(&hist8w[bi_ >> 2], 1u << ((bi_ & 3) << 3)); \
        int pos_ = base_[dL_] + (int)((old_ >> ((bi_ & 3) << 3)) & 0xFFu); \
        if (pos_ < STAGE) stage32[pos_] = (P); }
#pragma unroll
    for (int k = 0; k < NV4; k++) {
        PLACE1(rec4[k].x); PLACE1(rec4[k].y); PLACE1(rec4[k].z); PLACE1(rec4[k].w);
    }
    __syncthreads();
    // phase C (fused L1): 32 groups of 16 lanes, 4 dsts each; hist8w bytes are
    // inclusive prefixes -> c = byte diff; cnt-packed record back to stage32.
    const unsigned char* h8 = (const unsigned char*)hist8w;
    int grp = tid >> 4, l16 = tid & 15;
#pragma unroll
    for (int rd = 0; rd < 4; rd++) {
        int dL = grp + rd * 32;
        int segb = base_[dL];
        int sege = segb + hh[dL];
        if (sege > cntv) sege = cntv;
        float a0 = 0, a1 = 0, a2 = 0, a3 = 0, a4 = 0, a5 = 0;
        for (int q = segb + l16; q < sege; q += 16) {
            unsigned p = stage32[q];
            unsigned rel = (p >> 17) & 127u;
            unsigned bi = dL * 90u + rel;
            unsigned c = (unsigned)h8[bi] - (rel ? (unsigned)h8[bi - 1] : 0u);
            stage32[q] = (p & 0x00FFFFFFu) | (c << 24);
            float r = __builtin_amdgcn_rcpf((float)c);
            float4 xv = x4[p & 0x1FFFFu];
            unsigned rel2 = rel * 2u;
            float4 wa = w4[rel2], wb = w4[rel2 + 1];
            float x0 = xv.x * r, x1 = xv.y * r, x2 = xv.z * r;
            a0 += x0 * wa.x; a1 += x0 * wa.y;
            a2 += x1 * wa.z; a3 += x1 * wa.w;
            a4 += x2 * wb.x; a5 += x2 * wb.y;
        }
#pragma unroll
        for (int off = 8; off > 0; off >>= 1) {
            a0 += __shfl_down(a0, off); a1 += __shfl_down(a1, off); a2 += __shfl_down(a2, off);
            a3 += __shfl_down(a3, off); a4 += __shfl_down(a4, off); a5 += __shfl_down(a5, off);
        }
        if (l16 == 0) {
            int d = (b << BSH) + dL;
            if (d < N) {
                float4 xv = x4[d];
                float o[6] = {a0, a1, a2, a3, a4, a5};
#pragma unroll
                for (int j = 0; j < 6; j++)
                    o[j] = frelu(o[j] + xv.x * root[j] + xv.y * root[6 + j] +
                                 xv.z * root[12 + j] + bias[j]);
                __half2 p01 = __floats2half2_rn(o[0], o[1]);
                __half2 p23 = __floats2half2_rn(o[2], o[3]);
                __half2 p45 = __floats2half2_rn(o[4], o[5]);
                uint4 pk;
                pk.x = *(unsigned*)&p01;
                pk.y = *(unsigned*)&p23;
                pk.z = *(unsigned*)&p45;
                pk.w = 0u;
                h1h[d] = pk;
            }
        }
    }
    __syncthreads();
    // linear coalesced writeout of the sorted, cnt-packed records
    unsigned* regw = regions + (size_t)b * CAPB;
    int nv2 = (cntv + 3) >> 2;
    for (int i4 = tid; i4 < nv2; i4 += 512) {
        int i = i4 << 2;
        uint4 v;
        v.x = stage32[i];
        v.y = (i + 1 < cntv) ? stage32[i + 1] : SENT;
        v.z = (i + 2 < cntv) ? stage32[i + 2] : SENT;
        v.w = (i + 3 < cntv) ? stage32[i + 3] : SENT;
        *(uint4*)(regw + i) = v;
    }
}

// ---------- L2: predicated 4-unroll, SINGLE fp16 gather per edge ----------
__launch_bounds__(256)
__global__ void l2_g(const int2* __restrict__ rowseg, const unsigned* __restrict__ sorted,
                     const uint4* __restrict__ h1h, const float* __restrict__ W,
                     const float* __restrict__ root, const float* __restrict__ bias,
                     float4* __restrict__ h2p, int N) {
    __shared__ float4 w4[NREL * 2];
    for (int i = threadIdx.x; i < NREL * 2; i += 256) {
        int r = i >> 1;
        w4[i] = (i & 1) ? make_float4(W[r * 6 + 4], W[r * 6 + 5], 0.f, 0.f)
                        : make_float4(W[r * 6], W[r * 6 + 1], W[r * 6 + 2], W[r * 6 + 3]);
    }
    __syncthreads();
    int grp = threadIdx.x >> 4, l16 = threadIdx.x & 15;
    int d = blockIdx.x * LPD + grp;
    if (d >= N) return;
    int2 sg = rowseg[d];
    int beg = sg.x, end = sg.y;
    float a0 = 0, a1 = 0, a2 = 0;
    for (int i0 = beg + l16; i0 < end; i0 += 64) {
        unsigned p[4];
        float sc[4];
        uint4 hv[4];
#pragma unroll
        for (int k = 0; k < 4; k++) {       // predicated record loads
            int i = i0 + k * 16;
            int ic = i < end ? i : end - 1;
            p[k] = sorted[ic];
            sc[k] = i < end ? 1.0f : 0.0f;
        }
#pragma unroll
        for (int k = 0; k < 4; k++)         // 4 independent 16B gathers in flight
            hv[k] = h1h[p[k] & 0x1FFFFu];
#pragma unroll
        for (int k = 0; k < 4; k++) {
            unsigned rel2 = ((p[k] >> 17) & 127u) * 2u;
            float4 wa = w4[rel2], wb = w4[rel2 + 1];
            float2 f01 = __half22float2(*(__half2*)&hv[k].x);
            float2 f23 = __half22float2(*(__half2*)&hv[k].y);
            float2 f45 = __half22float2(*(__half2*)&hv[k].z);
            float m0 = f01.x * wa.x + f01.y * wa.y;
            float m1 = f23.x * wa.z + f23.y * wa.w;
            float m2 = f45.x * wb.x + f45.y * wb.y;
            a0 += sc[k] * m0; a1 += sc[k] * m1; a2 += sc[k] * m2;
        }
    }
#pragma unroll
    for (int off = 8; off > 0; off >>= 1) {
        a0 += __shfl_down(a0, off); a1 += __shfl_down(a1, off); a2 += __shfl_down(a2, off);
    }
    if (l16 == 0) {
        uint4 hd = h1h[d];
        float2 g01 = __half22float2(*(__half2*)&hd.x);
        float2 g23 = __half22float2(*(__half2*)&hd.y);
        float2 g45 = __half22float2(*(__half2*)&hd.z);
        float hv6[6] = {g01.x, g01.y, g23.x, g23.y, g45.x, g45.y};
        float o[3] = {a0, a1, a2};
#pragma unroll
        for (int j = 0; j < 3; j++) {
            float v = o[j] + bias[j];
#pragma unroll
            for (int k = 0; k < 6; k++) v += hv6[k] * root[k * 3 + j];
            o[j] = frelu(v);
        }
        h2p[d] = make_float4(o[0], o[1], o[2], 0.0f);
    }
}

// ---------- L3: predicated 4-unroll, mean via packed cnt, fused node + pool ----------
__launch_bounds__(256)
__global__ void l3_g(const int2* __restrict__ rowseg, const unsigned* __restrict__ sorted,
                     const float4* __restrict__ h2p, const float* __restrict__ W,
                     const float* __restrict__ root, const float* __restrict__ bias,
                     const int* __restrict__ batch, float* __restrict__ partials, int N) {
    __shared__ float4 w4[NREL * 2];
    __shared__ float redsm[LPD][8];
    for (int i = threadIdx.x; i < NREL * 2; i += 256) {
        int r = i >> 1;
        w4[i] = (i & 1) ? make_float4(W[r * 6 + 4], W[r * 6 + 5], 0.f, 0.f)
                        : make_float4(W[r * 6], W[r * 6 + 1], W[r * 6 + 2], W[r * 6 + 3]);
    }
    __syncthreads();
    int grp = threadIdx.x >> 4, l16 = threadIdx.x & 15;
    int d = blockIdx.x * LPD + grp;
    float a0 = 0, a1 = 0, a2 = 0, a3 = 0, a4 = 0, a5 = 0;
    if (d < N) {
        int2 sg = rowseg[d];
        int beg = sg.x, end = sg.y;
        for (int i0 = beg + l16; i0 < end; i0 += 64) {
            unsigned p[4];
            float sc[4];
            float4 xv[4];
#pragma unroll
            for (int k = 0; k < 4; k++) {   // predicated record loads
                int i = i0 + k * 16;
                int ic = i < end ? i : end - 1;
                p[k] = sorted[ic];
                sc[k] = i < end ? 1.0f : 0.0f;
            }
#pragma unroll
            for (int k = 0; k < 4; k++) xv[k] = h2p[p[k] & 0x1FFFFu];
#pragma unroll
            for (int k = 0; k < 4; k++) {
                // validity folds into the mean factor: zero r kills all 6 FMAs
                float r = sc[k] * __builtin_amdgcn_rcpf((float)(p[k] >> 24));
                unsigned rel2 = ((p[k] >> 17) & 127u) * 2u;
                float4 wa = w4[rel2], wb = w4[rel2 + 1];
                float x0 = xv[k].x * r, x1 = xv[k].y * r, x2 = xv[k].z * r;
                a0 += x0 * wa.x; a1 += x0 * wa.y;
                a2 += x1 * wa.z; a3 += x1 * wa.w;
                a4 += x2 * wb.x; a5 += x2 * wb.y;
            }
        }
    }
#pragma unroll
    for (int off = 8; off > 0; off >>= 1) {
        a0 += __shfl_down(a0, off); a1 += __shfl_down(a1, off); a2 += __shfl_down(a2, off);
        a3 += __shfl_down(a3, off); a4 += __shfl_down(a4, off); a5 += __shfl_down(a5, off);
    }
    if (l16 == 0) {
        float v[7] = {0, 0, 0, 0, 0, 0, 0};
        if (d < N && batch[d] == 0) {
            float4 xv = h2p[d];
            float o[6] = {a0, a1, a2, a3, a4, a5};
#pragma unroll
            for (int j = 0; j < 6; j++)
                v[j] = frelu(o[j] + xv.x * root[j] + xv.y * root[6 + j] +
                             xv.z * root[12 + j] + bias[j]);
            v[6] = 1.0f;
        }
#pragma unroll
        for (int k = 0; k < 7; k++) redsm[grp][k] = v[k];
    }
    __syncthreads();
    if (threadIdx.x < 7) {
        float t = 0;
#pragma unroll
        for (int g = 0; g < LPD; g++) t += redsm[g][threadIdx.x];
        partials[(size_t)blockIdx.x * 8 + threadIdx.x] = t;
    }
}

// ---------- finalize ----------
__global__ void pool_finalize(const float* __restrict__ partials, int nb,
                              float* __restrict__ out) {
    float v[7] = {0, 0, 0, 0, 0, 0, 0};
    for (int b = threadIdx.x; b < nb; b += blockDim.x) {
#pragma unroll
        for (int k = 0; k < 7; k++) v[k] += partials[(size_t)b * 8 + k];
    }
#pragma unroll
    for (int off = 32; off > 0; off >>= 1) {
#pragma unroll
        for (int k = 0; k < 7; k++) v[k] += __shfl_down(v[k], off);
    }
    __shared__ float sm[16][8];
    int wv = threadIdx.x >> 6, lane = threadIdx.x & 63;
    if (lane == 0) {
#pragma unroll
        for (int k = 0; k < 7; k++) sm[wv][k] = v[k];
    }
    __syncthreads();
    if (threadIdx.x == 0) {
        float t[7] = {0, 0, 0, 0, 0, 0, 0};
        int nw = blockDim.x >> 6;
        for (int q = 0; q < nw; q++) {
#pragma unroll
            for (int k = 0; k < 7; k++) t[k] += sm[q][k];
        }
        float c = t[6] < 1.0f ? 1.0f : t[6];
        float p[6], m = -1e30f;
#pragma unroll
        for (int j = 0; j < 6; j++) { p[j] = t[j] / c; m = fmaxf(m, p[j]); }
        float s = 0.0f;
#pragma unroll
        for (int j = 0; j < 6; j++) s += expf(p[j] - m);
        float lse = m + logf(s);
#pragma unroll
        for (int j = 0; j < 6; j++) out[j] = p[j] - lse;
    }
}

extern "C" void kernel_launch(void* const* d_in, const int* in_sizes, int n_in,
                              void* d_out, int out_size, void* d_ws, size_t ws_size,
                              hipStream_t stream) {
    const float* x     = (const float*)d_in[0];
    const int*   ei    = (const int*)d_in[1];
    const int*   batch = (const int*)d_in[2];
    const int*   etype = (const int*)d_in[3];
    const float* W1    = (const float*)d_in[4];
    const float* root1 = (const float*)d_in[5];
    const float* b1    = (const float*)d_in[6];
    const float* W2    = (const float*)d_in[7];
    const float* root2 = (const float*)d_in[8];
    const float* b2    = (const float*)d_in[9];
    const float* W3    = (const float*)d_in[10];
    const float* root3 = (const float*)d_in[11];
    const float* b3    = (const float*)d_in[12];

    const int N = in_sizes[0] / 3;
    const int E = in_sizes[1] / 2;
    const int* src = ei;
    const int* dst = ei + E;
    const int gG = (E + GCH - 1) / GCH;        // chunks (736 at E=6.4M)
    const int NBUCK = (N + BNODES - 1) >> BSH; // 782
    const int gL = (N + LPD - 1) / LPD;        // 6250

    char* ws = (char*)d_ws;
    size_t off = 0;
    auto alloc = [&](size_t bytes) -> void* {
        void* p = ws + off;
        off += (bytes + 255) & ~(size_t)255;
        return p;
    };
    int*      gcount  = (int*)     alloc(NBINS * sizeof(int));                 // zeroed
    size_t zero_bytes = off;
    unsigned* regions = (unsigned*)alloc((size_t)NBUCK * CAPB * sizeof(unsigned)); // 32.8MB
    int2*     rowseg  = (int2*)    alloc((size_t)N * sizeof(int2));            // 0.8MB
    float4*   x4      = (float4*)  alloc((size_t)N * sizeof(float4));          // 1.6MB
    uint4*    h1h     = (uint4*)   alloc((size_t)N * sizeof(uint4));           // 1.6MB
    float4*   h2p     = (float4*)  alloc((size_t)N * sizeof(float4));          // 1.6MB
    float*    partials = (float*)  alloc((size_t)gL * 8 * sizeof(float));
    // total ~39MB

    hipMemsetAsync(d_ws, 0, zero_bytes, stream);

    const int gNp = (N + 511) / 512;

    group_k<<<gNp + gG, 512, 0, stream>>>(x, x4, N, gNp, src, dst, etype,
                                          gcount, regions, E);
    sortb_l1_k<<<NBUCK, 512, 0, stream>>>(gcount, regions, rowseg,
                                          x4, W1, root1, b1, h1h, N);
    l2_g<<<gL, 256, 0, stream>>>(rowseg, regions, h1h, W2, root2, b2, h2p, N);
    l3_g<<<gL, 256, 0, stream>>>(rowseg, regions, h2p, W3, root3, b3, batch, partials, N);
    pool_finalize<<<1, 1024, 0, stream>>>(partials, gL, (float*)d_out);
}